// Round 8
// baseline (703.850 us; speedup 1.0000x reference)
//
#include <hip/hip_runtime.h>

#define S 2048
#define DM 1024
#define H 16
#define DH 64

typedef __attribute__((ext_vector_type(8))) short bf16x8;
typedef __attribute__((ext_vector_type(4))) float f32x4;
typedef __attribute__((ext_vector_type(16))) float f32x16;
typedef __attribute__((ext_vector_type(4))) unsigned short u16x4;
typedef __attribute__((ext_vector_type(4))) unsigned int u32x4;
typedef unsigned short u16;
typedef unsigned int u32;

// trunc-split: x = hi + rem; hi = upper-16(x) (exact), lo = RNE-bf16(rem).
__device__ __forceinline__ void split2(float x, u16& h, u16& l) {
  const u32 u = __float_as_uint(x);
  const u32 hu = u & 0xFFFF0000u;
  h = (u16)(hu >> 16);
  const float rem = x - __uint_as_float(hu);
  u32 r = __float_as_uint(rem);
  r += 0x7FFFu + ((r >> 16) & 1u);
  l = (u16)(r >> 16);
}
__device__ __forceinline__ void split2v(float x, u16x4& h4, u16x4& l4, int i) {
  u16 hh, ll;
  split2(x, hh, ll);
  h4[i] = hh; l4[i] = ll;
}
// pack two values' split-hi (trunc) into one u32 (a -> low16, b -> high16)
__device__ __forceinline__ u32 pack_split_hi(float a, float b) {
  return (__float_as_uint(a) >> 16) | (__float_as_uint(b) & 0xFFFF0000u);
}
// pack two values' split-lo (RNE of remainder)
__device__ __forceinline__ u32 pack_split_lo(float a, float b) {
  const float ra = a - __uint_as_float(__float_as_uint(a) & 0xFFFF0000u);
  const float rb = b - __uint_as_float(__float_as_uint(b) & 0xFFFF0000u);
  u32 ua = __float_as_uint(ra); ua += 0x7FFFu + ((ua >> 16) & 1u);
  u32 ub = __float_as_uint(rb); ub += 0x7FFFu + ((ub >> 16) & 1u);
  return (ua >> 16) | (ub & 0xFFFF0000u);
}

// c += (ah+al)*(bh+bl) dropping al*bl — 16x16x32 (proj kernels)
__device__ __forceinline__ f32x4 mfma3(bf16x8 ah, bf16x8 al, bf16x8 bh, bf16x8 bl, f32x4 c) {
  c = __builtin_amdgcn_mfma_f32_16x16x32_bf16(ah, bh, c, 0, 0, 0);
  c = __builtin_amdgcn_mfma_f32_16x16x32_bf16(ah, bl, c, 0, 0, 0);
  c = __builtin_amdgcn_mfma_f32_16x16x32_bf16(al, bh, c, 0, 0, 0);
  return c;
}
// same, 32x32x16 (attention)
__device__ __forceinline__ f32x16 mfma3w(bf16x8 ah, bf16x8 al, bf16x8 bh, bf16x8 bl, f32x16 c) {
  c = __builtin_amdgcn_mfma_f32_32x32x16_bf16(ah, bh, c, 0, 0, 0);
  c = __builtin_amdgcn_mfma_f32_32x32x16_bf16(ah, bl, c, 0, 0, 0);
  c = __builtin_amdgcn_mfma_f32_32x32x16_bf16(al, bh, c, 0, 0, 0);
  return c;
}

// ---------------- QKV projection: NT GEMM, split bf16 hi/lo output ----------
// z=0: Q head-major pre-scaled 0.125; z=1: K head-major; z=2: V^T [DM][S]
__global__ __launch_bounds__(256)
void qkv_proj(const float* __restrict__ q, const float* __restrict__ k,
              const float* __restrict__ v, const float* __restrict__ Wq,
              const float* __restrict__ Wk, const float* __restrict__ Wv,
              u16* __restrict__ qh, u16* __restrict__ ql,
              u16* __restrict__ kh, u16* __restrict__ kl,
              u16* __restrict__ vTh, u16* __restrict__ vTl)
{
  __shared__ u16 Ah[128][40], Al[128][40], Bh[128][40], Bl[128][40];
  const int tid = threadIdx.x;
  const int lane = tid & 63, w = tid >> 6;
  const int wr = w >> 1, wc = w & 1;
  const int lg = lane >> 4, lt = lane & 15;
  const int z = blockIdx.z;

  const float *A, *B;
  int m0, n0;
  if (z == 2) { A = Wv; B = v; m0 = blockIdx.y * 128; n0 = blockIdx.x * 128; }
  else {
    A = (z == 0) ? q : k; B = (z == 0) ? Wq : Wk;
    m0 = blockIdx.x * 128; n0 = blockIdx.y * 128;
  }

  f32x4 acc[4][4] = {};

  for (int k0 = 0; k0 < DM; k0 += 32) {
    float4 av[4], bv[4];
#pragma unroll
    for (int p = 0; p < 4; p++) {
      const int idx = p * 256 + tid;
      const int row = idx >> 3, c4 = (idx & 7) * 4;
      av[p] = *(const float4*)&A[(size_t)(m0 + row) * DM + k0 + c4];
      bv[p] = *(const float4*)&B[(size_t)(n0 + row) * DM + k0 + c4];
    }
    __syncthreads();
#pragma unroll
    for (int p = 0; p < 4; p++) {
      const int idx = p * 256 + tid;
      const int row = idx >> 3, c4 = (idx & 7) * 4;
      u16x4 h4, l4;
      split2v(av[p].x, h4, l4, 0); split2v(av[p].y, h4, l4, 1);
      split2v(av[p].z, h4, l4, 2); split2v(av[p].w, h4, l4, 3);
      *(u16x4*)&Ah[row][c4] = h4; *(u16x4*)&Al[row][c4] = l4;
      split2v(bv[p].x, h4, l4, 0); split2v(bv[p].y, h4, l4, 1);
      split2v(bv[p].z, h4, l4, 2); split2v(bv[p].w, h4, l4, 3);
      *(u16x4*)&Bh[row][c4] = h4; *(u16x4*)&Bl[row][c4] = l4;
    }
    __syncthreads();

    bf16x8 bhf[4], blf[4];
#pragma unroll
    for (int fj = 0; fj < 4; fj++) {
      const int r = wc * 64 + fj * 16 + lt;
      bhf[fj] = *(const bf16x8*)&Bh[r][lg * 8];
      blf[fj] = *(const bf16x8*)&Bl[r][lg * 8];
    }
#pragma unroll
    for (int fi = 0; fi < 4; fi++) {
      const int r = wr * 64 + fi * 16 + lt;
      const bf16x8 ahf = *(const bf16x8*)&Ah[r][lg * 8];
      const bf16x8 alf = *(const bf16x8*)&Al[r][lg * 8];
#pragma unroll
      for (int fj = 0; fj < 4; fj++)
        acc[fi][fj] = mfma3(ahf, alf, bhf[fj], blf[fj], acc[fi][fj]);
    }
  }

  u16 *dh, *dl;
  float scale;
  if (z == 0)      { dh = qh;  dl = ql;  scale = 0.125f; }
  else if (z == 1) { dh = kh;  dl = kl;  scale = 1.0f; }
  else             { dh = vTh; dl = vTl; scale = 1.0f; }

#pragma unroll
  for (int fi = 0; fi < 4; fi++)
#pragma unroll
    for (int r = 0; r < 4; r++) {
      const int m = m0 + wr * 64 + fi * 16 + lg * 4 + r;
#pragma unroll
      for (int fj = 0; fj < 4; fj++) {
        const int n = n0 + wc * 64 + fj * 16 + lt;
        const size_t addr = (z == 2) ? ((size_t)m * S + n)
                                     : ((size_t)((n >> 6) * S + m) * 64 + (n & 63));
        u16 hh, ll;
        split2(acc[fi][fj][r] * scale, hh, ll);
        dh[addr] = hh; dl[addr] = ll;
      }
    }
}

// ---------------- fused attention, 32x32x16 MFMA -----------------------------
// block = (64 q, head); 4 waves = (wq, wt) quadrants of [q 64][t 64].
// S^T = K·Q^T: D col = q = lane&31 (+wq*32), row = t = (reg&3)+8*(reg>>2)+4*hi
// (+wt*32). P exchanged lane<->lane^32 in-register (no P LDS). Per-wave online
// (m,l) over its t-half; merged once. PV partials merged across wt at the end.
__global__ __launch_bounds__(256, 3)
void attn_pv(const u16* __restrict__ qh, const u16* __restrict__ ql,
             const u16* __restrict__ kh, const u16* __restrict__ kl,
             const u16* __restrict__ vTh, const u16* __restrict__ vTl,
             const int* __restrict__ mask,
             float* __restrict__ attn, u16* __restrict__ ch, u16* __restrict__ cl)
{
  __shared__ u16 KV[4][64][72];            // [0]=Kh [1]=Kl [2]=Vh [3]=Vl (36.9 KB)
  __shared__ float mbuf[2][64], lbuf[2][64];
  float* sc = (float*)&KV[0][0][0];        // 16 KB overlay for PV merge

  const int tid = threadIdx.x;
  const int lane = tid & 63, w = tid >> 6;
  const int wq = w >> 1, wt = w & 1;
  const int l31 = lane & 31, hi = lane >> 5;
  const int h = blockIdx.y, s0 = blockIdx.x * 64;
  const int qrow = s0 + wq * 32 + l31;

  // Q B-fragments: n = q = l31(+wq*32), k(d) = ts*16 + hi*8 + j
  const size_t qbase = ((size_t)h * S + qrow) * 64;
  bf16x8 Qh_[4], Ql_[4];
#pragma unroll
  for (int ts = 0; ts < 4; ts++) {
    Qh_[ts] = *(const bf16x8*)&qh[qbase + ts * 16 + hi * 8];
    Ql_[ts] = *(const bf16x8*)&ql[qbase + ts * 16 + hi * 8];
  }

  const size_t kbase = (size_t)h * S * 64;
  const size_t vbase = (size_t)h * 64 * S;

  f32x16 ao0 = {}, ao1 = {};               // PV partials (d-half 0/1), this wave's t-range
  float m_run = -3.0e38f, l_run = 0.0f;

  // =============================== phase 1 ================================
  for (int t0 = 0; t0 < S; t0 += 64) {
    __syncthreads();
#pragma unroll
    for (int p = 0; p < 2; p++) {
      const int chunk = p * 256 + tid;
      const int row = chunk >> 3, c8 = (chunk & 7) * 8;
      *(uint4*)&KV[0][row][c8] = *(const uint4*)&kh[kbase + (size_t)(t0 + row) * 64 + c8];
      *(uint4*)&KV[1][row][c8] = *(const uint4*)&kl[kbase + (size_t)(t0 + row) * 64 + c8];
      *(uint4*)&KV[2][row][c8] = *(const uint4*)&vTh[vbase + (size_t)row * S + t0 + c8];
      *(uint4*)&KV[3][row][c8] = *(const uint4*)&vTl[vbase + (size_t)row * S + t0 + c8];
    }
    __syncthreads();

    // issue mask loads early; latency hides under QK^T MFMAs
    const int* mrow = &mask[(size_t)qrow * S + t0 + wt * 32 + hi * 4];
    const int4 mv0 = *(const int4*)&mrow[0];
    const int4 mv1 = *(const int4*)&mrow[8];
    const int4 mv2 = *(const int4*)&mrow[16];
    const int4 mv3 = *(const int4*)&mrow[24];

    // QK^T quadrant: A = K rows (t = wt*32+l31), k(d) = ts*16+hi*8+j
    f32x16 sct = {};
#pragma unroll
    for (int ts = 0; ts < 4; ts++) {
      const bf16x8 ah = *(const bf16x8*)&KV[0][wt * 32 + l31][ts * 16 + hi * 8];
      const bf16x8 al = *(const bf16x8*)&KV[1][wt * 32 + l31][ts * 16 + hi * 8];
      sct = mfma3w(ah, al, Qh_[ts], Ql_[ts], sct);
    }

    // mask (reference quirk: masked -> -1e-7); reg 4g+j holds t = 8g+4hi+j
#define MSK(G, MV)                                              \
    sct[4*G+0] = MV.x ? -1e-7f : sct[4*G+0];                    \
    sct[4*G+1] = MV.y ? -1e-7f : sct[4*G+1];                    \
    sct[4*G+2] = MV.z ? -1e-7f : sct[4*G+2];                    \
    sct[4*G+3] = MV.w ? -1e-7f : sct[4*G+3];
    MSK(0, mv0) MSK(1, mv1) MSK(2, mv2) MSK(3, mv3)

    // online (m,l): q-row's 64 t-values live in this lane + lane^32
    float pm = sct[0];
#pragma unroll
    for (int r = 1; r < 16; r++) pm = fmaxf(pm, sct[r]);
    pm = fmaxf(pm, __shfl_xor(pm, 32));
    const float mn = fmaxf(m_run, pm);
    float es = 0.0f;
#pragma unroll
    for (int r = 0; r < 16; r++) es += __expf(sct[r] - mn);
    es += __shfl_xor(es, 32);
    l_run = l_run * __expf(m_run - mn) + es;
    m_run = mn;

    // pack P (split hi/lo) and exchange halves in-register
    u32 ph0[4], ph1[4], pl0[4], pl1[4];
#pragma unroll
    for (int b = 0; b < 4; b++) {
      ph0[b] = pack_split_hi(sct[4*b+0], sct[4*b+1]);
      ph1[b] = pack_split_hi(sct[4*b+2], sct[4*b+3]);
      pl0[b] = pack_split_lo(sct[4*b+0], sct[4*b+1]);
      pl1[b] = pack_split_lo(sct[4*b+2], sct[4*b+3]);
    }
    u32 sph0[4], sph1[4], spl0[4], spl1[4];
#pragma unroll
    for (int b = 0; b < 4; b++) {
      sph0[b] = (u32)__shfl_xor((int)ph0[b], 32);
      sph1[b] = (u32)__shfl_xor((int)ph1[b], 32);
      spl0[b] = (u32)__shfl_xor((int)pl0[b], 32);
      spl1[b] = (u32)__shfl_xor((int)pl1[b], 32);
    }

    // PV: A = P[q][t] (regs), B = V^T[d][t] (LDS). k-step ts2 over wave's 32 t.
#pragma unroll
    for (int ts2 = 0; ts2 < 2; ts2++) {
      const int b = 2 * ts2 + hi;
      u32x4 wh, wl;
      wh[0] = hi ? sph0[b] : ph0[b];  wh[1] = hi ? sph1[b] : ph1[b];
      wh[2] = hi ? ph0[b] : sph0[b];  wh[3] = hi ? ph1[b] : sph1[b];
      wl[0] = hi ? spl0[b] : pl0[b];  wl[1] = hi ? spl1[b] : pl1[b];
      wl[2] = hi ? pl0[b] : spl0[b];  wl[3] = hi ? pl1[b] : spl1[b];
      const bf16x8 pa_h = __builtin_bit_cast(bf16x8, wh);
      const bf16x8 pa_l = __builtin_bit_cast(bf16x8, wl);

      const int tc = wt * 32 + ts2 * 16 + hi * 8;
      const bf16x8 vbh0 = *(const bf16x8*)&KV[2][l31][tc];
      const bf16x8 vbl0 = *(const bf16x8*)&KV[3][l31][tc];
      const bf16x8 vbh1 = *(const bf16x8*)&KV[2][32 + l31][tc];
      const bf16x8 vbl1 = *(const bf16x8*)&KV[3][32 + l31][tc];
      ao0 = mfma3w(pa_h, pa_l, vbh0, vbl0, ao0);
      ao1 = mfma3w(pa_h, pa_l, vbh1, vbl1, ao1);
    }
  }

  // ---- merge stats across wt; merge PV partials across wt; write concat ----
  __syncthreads();                          // all phase-1 LDS reads complete
  if (hi == 0) {
    mbuf[wt][wq * 32 + l31] = m_run;
    lbuf[wt][wq * 32 + l31] = l_run;
  }
  if (wt == 1) {
#pragma unroll
    for (int r = 0; r < 16; r++) {
      const int qloc = wq * 32 + (r & 3) + 8 * (r >> 2) + 4 * hi;
      sc[qloc * 64 + l31]      = ao0[r];
      sc[qloc * 64 + 32 + l31] = ao1[r];
    }
  }
  __syncthreads();
  const float m0_ = mbuf[0][wq * 32 + l31], m1_ = mbuf[1][wq * 32 + l31];
  const float l0_ = lbuf[0][wq * 32 + l31], l1_ = lbuf[1][wq * 32 + l31];
  const float fm  = fmaxf(m0_, m1_);
  const float fil = 1.0f / (l0_ * __expf(m0_ - fm) + l1_ * __expf(m1_ - fm));
  if (wt == 0) {
#pragma unroll
    for (int r = 0; r < 16; r++) {
      const int qloc = wq * 32 + (r & 3) + 8 * (r >> 2) + 4 * hi;
      const float o0 = ao0[r] + sc[qloc * 64 + l31];
      const float o1 = ao1[r] + sc[qloc * 64 + 32 + l31];
      u16 hh, ll;
      split2(o0, hh, ll);
      ch[(size_t)(s0 + qloc) * DM + h * 64 + l31] = hh;
      cl[(size_t)(s0 + qloc) * DM + h * 64 + l31] = ll;
      split2(o1, hh, ll);
      ch[(size_t)(s0 + qloc) * DM + h * 64 + 32 + l31] = hh;
      cl[(size_t)(s0 + qloc) * DM + h * 64 + 32 + l31] = ll;
    }
  }

  // ===== phase 2: recompute QK^T, write normalized softmax exactly once =====
  for (int t0 = 0; t0 < S; t0 += 64) {
    __syncthreads();                        // prev reads (incl. sc merge) done
#pragma unroll
    for (int p = 0; p < 2; p++) {
      const int chunk = p * 256 + tid;
      const int row = chunk >> 3, c8 = (chunk & 7) * 8;
      *(uint4*)&KV[0][row][c8] = *(const uint4*)&kh[kbase + (size_t)(t0 + row) * 64 + c8];
      *(uint4*)&KV[1][row][c8] = *(const uint4*)&kl[kbase + (size_t)(t0 + row) * 64 + c8];
    }
    __syncthreads();

    const int* mrow = &mask[(size_t)qrow * S + t0 + wt * 32 + hi * 4];
    const int4 mv0 = *(const int4*)&mrow[0];
    const int4 mv1 = *(const int4*)&mrow[8];
    const int4 mv2 = *(const int4*)&mrow[16];
    const int4 mv3 = *(const int4*)&mrow[24];

    f32x16 sct = {};
#pragma unroll
    for (int ts = 0; ts < 4; ts++) {
      const bf16x8 ah = *(const bf16x8*)&KV[0][wt * 32 + l31][ts * 16 + hi * 8];
      const bf16x8 al = *(const bf16x8*)&KV[1][wt * 32 + l31][ts * 16 + hi * 8];
      sct = mfma3w(ah, al, Qh_[ts], Ql_[ts], sct);
    }
    MSK(0, mv0) MSK(1, mv1) MSK(2, mv2) MSK(3, mv3)
#undef MSK

    float* arow = &attn[((size_t)h * S + qrow) * S + t0 + wt * 32 + 4 * hi];
#pragma unroll
    for (int g = 0; g < 4; g++) {
      float4 o;
      o.x = __expf(sct[4*g+0] - fm) * fil;
      o.y = __expf(sct[4*g+1] - fm) * fil;
      o.z = __expf(sct[4*g+2] - fm) * fil;
      o.w = __expf(sct[4*g+3] - fm) * fil;
      *(float4*)&arow[8 * g] = o;
    }
  }
}

// ---------------- output projection: A pre-split concat, B = Wo fp32 --------
__global__ __launch_bounds__(256)
void out_proj(const u16* __restrict__ ch, const u16* __restrict__ cl,
              const float* __restrict__ Wo, float* __restrict__ out)
{
  __shared__ u16 Ah[128][40], Al[128][40], Bh[128][40], Bl[128][40];
  const int tid = threadIdx.x;
  const int lane = tid & 63, w = tid >> 6;
  const int wr = w >> 1, wc = w & 1;
  const int lg = lane >> 4, lt = lane & 15;
  const int m0 = blockIdx.x * 128, n0 = blockIdx.y * 128;

  f32x4 acc[4][4] = {};

  for (int k0 = 0; k0 < DM; k0 += 32) {
    uint4 ahv[2], alv[2];
    float4 bv[4];
#pragma unroll
    for (int p = 0; p < 2; p++) {
      const int chunk = p * 256 + tid;
      const int row = chunk >> 2, c8 = (chunk & 3) * 8;
      ahv[p] = *(const uint4*)&ch[(size_t)(m0 + row) * DM + k0 + c8];
      alv[p] = *(const uint4*)&cl[(size_t)(m0 + row) * DM + k0 + c8];
    }
#pragma unroll
    for (int p = 0; p < 4; p++) {
      const int idx = p * 256 + tid;
      const int row = idx >> 3, c4 = (idx & 7) * 4;
      bv[p] = *(const float4*)&Wo[(size_t)(n0 + row) * DM + k0 + c4];
    }
    __syncthreads();
#pragma unroll
    for (int p = 0; p < 2; p++) {
      const int chunk = p * 256 + tid;
      const int row = chunk >> 2, c8 = (chunk & 3) * 8;
      *(uint4*)&Ah[row][c8] = ahv[p];
      *(uint4*)&Al[row][c8] = alv[p];
    }
#pragma unroll
    for (int p = 0; p < 4; p++) {
      const int idx = p * 256 + tid;
      const int row = idx >> 3, c4 = (idx & 7) * 4;
      u16x4 h4, l4;
      split2v(bv[p].x, h4, l4, 0); split2v(bv[p].y, h4, l4, 1);
      split2v(bv[p].z, h4, l4, 2); split2v(bv[p].w, h4, l4, 3);
      *(u16x4*)&Bh[row][c4] = h4; *(u16x4*)&Bl[row][c4] = l4;
    }
    __syncthreads();

    bf16x8 bhf[4], blf[4];
#pragma unroll
    for (int fj = 0; fj < 4; fj++) {
      const int r = wc * 64 + fj * 16 + lt;
      bhf[fj] = *(const bf16x8*)&Bh[r][lg * 8];
      blf[fj] = *(const bf16x8*)&Bl[r][lg * 8];
    }
#pragma unroll
    for (int fi = 0; fi < 4; fi++) {
      const int r = wr * 64 + fi * 16 + lt;
      const bf16x8 ahf = *(const bf16x8*)&Ah[r][lg * 8];
      const bf16x8 alf = *(const bf16x8*)&Al[r][lg * 8];
#pragma unroll
      for (int fj = 0; fj < 4; fj++)
        acc[fi][fj] = mfma3(ahf, alf, bhf[fj], blf[fj], acc[fi][fj]);
    }
  }

#pragma unroll
  for (int fi = 0; fi < 4; fi++)
#pragma unroll
    for (int r = 0; r < 4; r++) {
      const int m = m0 + wr * 64 + fi * 16 + lg * 4 + r;
#pragma unroll
      for (int fj = 0; fj < 4; fj++) {
        const int n = n0 + wc * 64 + fj * 16 + lt;
        out[(size_t)m * DM + n] = acc[fi][fj][r];
      }
    }
}

// ---------------------------------------------------------------------------
extern "C" void kernel_launch(void* const* d_in, const int* in_sizes, int n_in,
                              void* d_out, int out_size, void* d_ws, size_t ws_size,
                              hipStream_t stream)
{
  const float* query = (const float*)d_in[0];
  const float* key   = (const float*)d_in[1];
  const float* value = (const float*)d_in[2];
  const int*   mask  = (const int*)d_in[3];
  const float* Wq    = (const float*)d_in[4];
  const float* Wk    = (const float*)d_in[5];
  const float* Wv    = (const float*)d_in[6];
  const float* Wo    = (const float*)d_in[7];

  float* out  = (float*)d_out;                 // [S][DM]
  float* attn = out + (size_t)S * DM;          // [H][S][S]

  const size_t NE = (size_t)H * S * 64;        // 2,097,152
  u16* qh  = (u16*)d_ws;                       // 8 arrays x 4 MB = 32 MB
  u16* ql  = qh  + NE;
  u16* kh  = ql  + NE;
  u16* kl  = kh  + NE;
  u16* vTh = kl  + NE;                         // [DM][S]
  u16* vTl = vTh + NE;
  u16* ch  = vTl + NE;                         // [S][DM]
  u16* cl  = ch  + NE;

  hipLaunchKernelGGL(qkv_proj, dim3(16, 8, 3), dim3(256), 0, stream,
                     query, key, value, Wq, Wk, Wv, qh, ql, kh, kl, vTh, vTl);

  hipLaunchKernelGGL(attn_pv, dim3(S / 64, H), dim3(256), 0, stream,
                     qh, ql, kh, kl, vTh, vTl, mask, attn, ch, cl);

  hipLaunchKernelGGL(out_proj, dim3(16, 8), dim3(256), 0, stream,
                     ch, cl, Wo, out);
}